// Round 4
// baseline (425.059 us; speedup 1.0000x reference)
//
#include <hip/hip_runtime.h>

// SSIM loss: horizontal conv via in-wave ds_bpermute + register-rotating
// vertical conv. Zero LDS tiles, zero main-loop barriers. fp32.
// Shapes fixed by reference: (32,3,512,512) fp32 inputs, scalar fp32 output.

constexpr int W   = 512;
constexpr int H   = 512;
constexpr int NCH = 96;        // 32*3 planes
constexpr int WO  = 502;       // valid-conv output width/height
constexpr int SOUT = 118;      // output cols per wave-strip (64 lanes * 2 - 10)
constexpr int NSTRIP = 5;      // ceil(502/118)
constexpr int ORB  = 64;       // output rows per band
constexpr int NBAND = 8;       // ceil(502/64)
constexpr int NWAVE = NSTRIP * NBAND * NCH;  // 3840

// normalized 1-D gaussian (sigma=1.5, K=11) as exact fp32 literals
__device__ __constant__ const float GW[11] = {
  0.0010283885f, 0.0075987582f, 0.0360008058f, 0.1093606695f, 0.2130055279f,
  0.2660116484f,
  0.2130055279f, 0.1093606695f, 0.0360008058f, 0.0075987582f, 0.0010283885f};

__device__ __forceinline__ unsigned fkey(float f) {
  unsigned u = __float_as_uint(f);
  return (u & 0x80000000u) ? ~u : (u | 0x80000000u);
}
__device__ __forceinline__ float funkey(unsigned k) {
  unsigned u = (k & 0x80000000u) ? (k & 0x7FFFFFFFu) : ~k;
  return __uint_as_float(u);
}
__device__ __forceinline__ float bperm(int byteidx, float v) {
  return __int_as_float(__builtin_amdgcn_ds_bpermute(byteidx, __float_as_int(v)));
}

__global__ void init_ws_kernel(unsigned* ws) {
  ws[0] = 0u;             // running max key
  ws[1] = 0xFFFFFFFFu;    // running min key
  ((float*)ws)[2] = 0.0f; // ssim sum
}

__global__ __launch_bounds__(256) void minmax_kernel(
    const float4* __restrict__ x, unsigned* __restrict__ ws, int n4) {
  const int tid = threadIdx.x;
  const int gid = blockIdx.x * 256 + tid;
  const int S = gridDim.x * 256;
  float mx = -3.4e38f, mn = 3.4e38f;
  for (int i = gid; i < n4; i += 4 * S) {
    float4 v0 = x[i];
    float4 v1 = (i + S     < n4) ? x[i + S]     : v0;
    float4 v2 = (i + 2 * S < n4) ? x[i + 2 * S] : v0;
    float4 v3 = (i + 3 * S < n4) ? x[i + 3 * S] : v0;
    mx = fmaxf(mx, fmaxf(fmaxf(fmaxf(v0.x, v0.y), fmaxf(v0.z, v0.w)),
                         fmaxf(fmaxf(v1.x, v1.y), fmaxf(v1.z, v1.w))));
    mx = fmaxf(mx, fmaxf(fmaxf(fmaxf(v2.x, v2.y), fmaxf(v2.z, v2.w)),
                         fmaxf(fmaxf(v3.x, v3.y), fmaxf(v3.z, v3.w))));
    mn = fminf(mn, fminf(fminf(fminf(v0.x, v0.y), fminf(v0.z, v0.w)),
                         fminf(fminf(v1.x, v1.y), fminf(v1.z, v1.w))));
    mn = fminf(mn, fminf(fminf(fminf(v2.x, v2.y), fminf(v2.z, v2.w)),
                         fminf(fminf(v3.x, v3.y), fminf(v3.z, v3.w))));
  }
  #pragma unroll
  for (int off = 32; off; off >>= 1) {
    mx = fmaxf(mx, __shfl_down(mx, off));
    mn = fminf(mn, __shfl_down(mn, off));
  }
  __shared__ float smx[4], smn[4];
  const int lane = tid & 63, wib = tid >> 6;
  if (lane == 0) { smx[wib] = mx; smn[wib] = mn; }
  __syncthreads();
  if (tid == 0) {
    mx = fmaxf(fmaxf(smx[0], smx[1]), fmaxf(smx[2], smx[3]));
    mn = fminf(fminf(smn[0], smn[1]), fminf(smn[2], smn[3]));
    atomicMax(&ws[0], fkey(mx));
    atomicMin(&ws[1], fkey(mn));
  }
}

__global__ __launch_bounds__(256) void ssim_kernel(
    const float* __restrict__ img1, const float* __restrict__ img2,
    const unsigned* __restrict__ wsk, float* __restrict__ sum_out) {
  const int tid  = threadIdx.x;
  const int lane = tid & 63;
  const int wib  = tid >> 6;
  const int wid  = blockIdx.x * 4 + wib;   // 0..3839

  const int strip = wid % NSTRIP;
  const int band  = (wid / NSTRIP) % NBAND;
  const int plane = wid / (NSTRIP * NBAND);

  const int O0 = strip * SOUT;         // strip input/output col base
  const int r0 = band * ORB;           // band output-row base
  const int c0 = O0 + (lane << 1);     // this lane's input col pair
  const bool cok = (c0 < W);           // c0 even -> c0+1 < W too

  const float* p1 = img1 + (size_t)plane * (H * W);
  const float* p2 = img2 + (size_t)plane * (H * W);

  // dynamic range -> C1, C2 (wave-uniform)
  const float maxv = funkey(wsk[0]);
  const float minv = funkey(wsk[1]);
  const float L = (maxv > 128.0f ? 255.0f : 1.0f) - (minv < -0.5f ? -1.0f : 0.0f);
  float C1 = 0.01f * L; C1 *= C1;
  float C2 = 0.03f * L; C2 *= C2;

  // bpermute byte indices (precomputed, reused every row)
  const int im3 = ((lane - 3) & 63) << 2;
  const int im2 = ((lane - 2) & 63) << 2;
  const int im1 = ((lane - 1) & 63) << 2;
  const int ip1 = ((lane + 1) & 63) << 2;
  const int ip2 = ((lane + 2) & 63) << 2;

  // rotating 11-slot vertical accumulators: 5 quantities x 2 cols
  float acc[11][5][2];
  #pragma unroll
  for (int s = 0; s < 11; ++s)
    #pragma unroll
    for (int q = 0; q < 5; ++q) { acc[s][q][0] = 0.f; acc[s][q][1] = 0.f; }

  float lsum = 0.f;

  // prefetch first row (r0 <= 448 < H always)
  float na0 = 0.f, na1 = 0.f, nb0 = 0.f, nb1 = 0.f;
  if (cok) {
    float2 t1 = *reinterpret_cast<const float2*>(p1 + (size_t)r0 * W + c0);
    float2 t2 = *reinterpret_cast<const float2*>(p2 + (size_t)r0 * W + c0);
    na0 = t1.x; na1 = t1.y; nb0 = t2.x; nb1 = t2.y;
  }

  #pragma unroll 1
  for (int g = 0; g < 7; ++g) {
    #pragma unroll
    for (int p = 0; p < 11; ++p) {
      const float ca0 = na0, ca1 = na1, cb0 = nb0, cb1 = nb1;

      // software prefetch of next row
      const int rn = r0 + 11 * g + p + 1;
      if ((rn < H) && cok) {
        float2 t1 = *reinterpret_cast<const float2*>(p1 + (size_t)rn * W + c0);
        float2 t2 = *reinterpret_cast<const float2*>(p2 + (size_t)rn * W + c0);
        na0 = t1.x; na1 = t1.y; nb0 = t2.x; nb1 = t2.y;
      } else {
        na0 = 0.f; na1 = 0.f; nb0 = 0.f; nb1 = 0.f;
      }

      // 12-value windows: cols c0-6 .. c0+5, from lanes l-3..l+2 (2 vals each)
      float wa[12], wb[12];
      wa[6] = ca0; wa[7] = ca1; wb[6] = cb0; wb[7] = cb1;
      wa[0]  = bperm(im3, ca0); wa[1]  = bperm(im3, ca1);
      wa[2]  = bperm(im2, ca0); wa[3]  = bperm(im2, ca1);
      wa[4]  = bperm(im1, ca0); wa[5]  = bperm(im1, ca1);
      wa[8]  = bperm(ip1, ca0); wa[9]  = bperm(ip1, ca1);
      wa[10] = bperm(ip2, ca0); wa[11] = bperm(ip2, ca1);
      wb[0]  = bperm(im3, cb0); wb[1]  = bperm(im3, cb1);
      wb[2]  = bperm(im2, cb0); wb[3]  = bperm(im2, cb1);
      wb[4]  = bperm(im1, cb0); wb[5]  = bperm(im1, cb1);
      wb[8]  = bperm(ip1, cb0); wb[9]  = bperm(ip1, cb1);
      wb[10] = bperm(ip2, cb0); wb[11] = bperm(ip2, cb1);

      // horizontal conv: h[q][c] = sum_k GW[k] * win_q[k+c], c=0,1
      float h[5][2];
      h[0][0] = 0.f; h[0][1] = 0.f; h[1][0] = 0.f; h[1][1] = 0.f;
      #pragma unroll
      for (int k = 0; k < 11; ++k) {
        h[0][0] = fmaf(GW[k], wa[k],     h[0][0]);
        h[0][1] = fmaf(GW[k], wa[k + 1], h[0][1]);
        h[1][0] = fmaf(GW[k], wb[k],     h[1][0]);
        h[1][1] = fmaf(GW[k], wb[k + 1], h[1][1]);
      }
      {
        float sq[12];
        #pragma unroll
        for (int m = 0; m < 12; ++m) sq[m] = wa[m] * wa[m];
        h[2][0] = 0.f; h[2][1] = 0.f;
        #pragma unroll
        for (int k = 0; k < 11; ++k) {
          h[2][0] = fmaf(GW[k], sq[k],     h[2][0]);
          h[2][1] = fmaf(GW[k], sq[k + 1], h[2][1]);
        }
      }
      {
        float sq[12];
        #pragma unroll
        for (int m = 0; m < 12; ++m) sq[m] = wb[m] * wb[m];
        h[3][0] = 0.f; h[3][1] = 0.f;
        #pragma unroll
        for (int k = 0; k < 11; ++k) {
          h[3][0] = fmaf(GW[k], sq[k],     h[3][0]);
          h[3][1] = fmaf(GW[k], sq[k + 1], h[3][1]);
        }
      }
      {
        float sq[12];
        #pragma unroll
        for (int m = 0; m < 12; ++m) sq[m] = wa[m] * wb[m];
        h[4][0] = 0.f; h[4][1] = 0.f;
        #pragma unroll
        for (int k = 0; k < 11; ++k) {
          h[4][0] = fmaf(GW[k], sq[k],     h[4][0]);
          h[4][1] = fmaf(GW[k], sq[k + 1], h[4][1]);
        }
      }

      // vertical rotating accumulate (static indices after full unroll)
      #pragma unroll
      for (int s = 0; s < 11; ++s) {
        const float wv = GW[(p - s + 11) % 11];
        #pragma unroll
        for (int q = 0; q < 5; ++q) {
          acc[s][q][0] = fmaf(wv, h[q][0], acc[s][q][0]);
          acc[s][q][1] = fmaf(wv, h[q][1], acc[s][q][1]);
        }
      }

      // slot (p+1)%11 completed: output row = r0 + 11g + p - 10
      const int es = (p + 1) % 11;
      const int ol = 11 * g + p - 10;
      const int orow = r0 + ol;
      if (ol >= 0 && ol < ORB && orow < WO) {   // wave-uniform
        #pragma unroll
        for (int c = 0; c < 2; ++c) {
          const int ocol = c0 - 6 + c;
          const bool valid = (lane >= 3) && (lane <= 61) && (ocol < WO);
          const float mu1 = acc[es][0][c], mu2 = acc[es][1][c];
          const float m11 = mu1 * mu1, m22 = mu2 * mu2, m12 = mu1 * mu2;
          const float s11 = acc[es][2][c] - m11;
          const float s22 = acc[es][3][c] - m22;
          const float s12 = acc[es][4][c] - m12;
          const float num = (2.f * m12 + C1) * (2.f * s12 + C2);
          const float den = (m11 + m22 + C1) * (s11 + s22 + C2);
          lsum += valid ? num * __builtin_amdgcn_rcpf(den) : 0.f;
        }
      }
      #pragma unroll
      for (int q = 0; q < 5; ++q) { acc[es][q][0] = 0.f; acc[es][q][1] = 0.f; }
    }
  }

  // wave reduce + per-block single atomic
  #pragma unroll
  for (int off = 32; off; off >>= 1) lsum += __shfl_down(lsum, off);
  __shared__ float bsum[4];
  if (lane == 0) bsum[wib] = lsum;
  __syncthreads();
  if (tid == 0) atomicAdd(sum_out, bsum[0] + bsum[1] + bsum[2] + bsum[3]);
}

__global__ void finalize_kernel(const float* __restrict__ sum, float* __restrict__ out) {
  out[0] = 1.0f - sum[0] * (1.0f / 24192384.0f);  // 96*502*502
}

extern "C" void kernel_launch(void* const* d_in, const int* in_sizes, int n_in,
                              void* d_out, int out_size, void* d_ws, size_t ws_size,
                              hipStream_t stream) {
  const float* img1 = (const float*)d_in[0];
  const float* img2 = (const float*)d_in[1];
  float* out = (float*)d_out;
  unsigned* ws = (unsigned*)d_ws;

  init_ws_kernel<<<1, 1, 0, stream>>>(ws);

  int n4 = in_sizes[0] >> 2;
  minmax_kernel<<<2048, 256, 0, stream>>>((const float4*)img1, ws, n4);

  ssim_kernel<<<NWAVE / 4, 256, 0, stream>>>(img1, img2, ws, (float*)ws + 2);

  finalize_kernel<<<1, 1, 0, stream>>>((const float*)ws + 2, out);
}